// Round 6
// baseline (974.394 us; speedup 1.0000x reference)
//
#include <hip/hip_runtime.h>
#include <math.h>

#define NB 16
#define INW 256
#define GN 100
#define NV (GN*GN)          // 10000
#define NPROB (NB*2)        // 32
#define K_TOP 20
#define HSZ 8192
#define HMASK (HSZ-1)
#define EMPTYK 0xFFFFFFFFu
#define KB 16               // value-range buckets per problem
#define RCAP 6144           // max regions per problem
#define MYCAP 4096          // max edges per bucket
#define LISTCAP 8192        // max bars per problem
#define NBIN 4096

// ws byte offsets
#define OFF_RES   0               // NB*NV f32 = 640000
#define OFF_LAB   640000          // NPROB*NV u16 = 640000
#define OFF_DENSE 1280000         // NPROB*NV u16 = 640000
#define OFF_D2O   1920000         // NPROB*RCAP u64 = 1572864
#define OFF_EDGES 3492864         // NPROB*HSZ u64 = 2097152
#define OFF_ECNT  5590016         // NPROB u32
#define OFF_RCNT  5590144         // NPROB u32
#define OFF_SPLIT 5590272         // NPROB*KB u32 = 2048
#define OFF_LCNT  5592320         // NPROB u32
#define OFF_LIST  5592448         // NPROB*LISTCAP f32 = 1048576
#define OFF_PART  6641024         // NPROB f32

__device__ __forceinline__ int imin(int a, int b){ return a < b ? a : b; }
__device__ __forceinline__ int imax(int a, int b){ return a > b ? a : b; }

__device__ __forceinline__ unsigned mono32(float f){
  unsigned b = __float_as_uint(f);
  return (b & 0x80000000u) ? ~b : (b | 0x80000000u);
}
__device__ __forceinline__ float unmono(unsigned m){
  unsigned b = (m & 0x80000000u) ? (m ^ 0x80000000u) : ~m;
  return __uint_as_float(b);
}

// keys-cubic a=-0.5 weights for one output coord (renormalized over valid taps)
__device__ __forceinline__ void cub_w(int i, int& j0, float w[4]) {
  double inv = (double)INW / (double)GN;
  double sf  = ((double)i + 0.5) * inv - 0.5;
  j0 = (int)floor(sf) - 1;
  double wd[4]; double s = 0.0;
  #pragma unroll
  for (int k = 0; k < 4; ++k) {
    int j = j0 + k;
    double t = fabs(sf - (double)j);
    double v;
    if (t < 1.0)      v = ((1.5*t - 2.5)*t)*t + 1.0;
    else if (t < 2.0) v = ((-0.5*t + 2.5)*t - 4.0)*t + 2.0;
    else              v = 0.0;
    if (j < 0 || j >= INW) v = 0.0;
    wd[k] = v; s += v;
  }
  #pragma unroll
  for (int k = 0; k < 4; ++k) w[k] = (float)(wd[k] / s);
}

// ---------------------------------------------------------------------------
// Kernel 1: separable bicubic resize 256x256 -> 100x100 (weights inline)
// ---------------------------------------------------------------------------
__global__ __launch_bounds__(256) void resize_k(const float* __restrict__ in, float* ws) {
  float* outp = (float*)((char*)ws + OFF_RES);
  int idx = blockIdx.x * 256 + threadIdx.x;
  if (idx >= NB * NV) return;
  int b = idx / NV; int rem = idx - b * NV;
  int i = rem / GN; int j = rem - i * GN;
  const float* img = in + (size_t)b * INW * INW;
  int r0, c0; float wr[4], wc[4];
  cub_w(i, r0, wr);
  cub_w(j, c0, wc);
  float acc = 0.f;
  #pragma unroll
  for (int kr = 0; kr < 4; ++kr) {
    int rr = imin(imax(r0 + kr, 0), INW - 1);
    const float* row = img + rr * INW;
    int c0c = imin(imax(c0 + 0, 0), INW - 1);
    int c1c = imin(imax(c0 + 1, 0), INW - 1);
    int c2c = imin(imax(c0 + 2, 0), INW - 1);
    int c3c = imin(imax(c0 + 3, 0), INW - 1);
    float rs = wc[0]*row[c0c] + wc[1]*row[c1c] + wc[2]*row[c2c] + wc[3]*row[c3c];
    acc += wr[kr] * rs;
  }
  outp[idx] = acc;
}

// ---------------------------------------------------------------------------
// Kernel 2: watershed labels + dense region rename + peak-ord table
// ---------------------------------------------------------------------------
__global__ __launch_bounds__(256) void label_rename_k(float* ws) {
  __shared__ unsigned sm[NV];
  __shared__ unsigned short lab[NV];
  __shared__ unsigned cnt[256];
  int p = blockIdx.x, samp = p >> 1, neg = p & 1, tid = threadIdx.x;
  const float* res = (const float*)((const char*)ws + OFF_RES) + samp * NV;
  unsigned short* glab = (unsigned short*)((char*)ws + OFF_LAB) + (size_t)p * NV;
  unsigned short* dense = (unsigned short*)((char*)ws + OFF_DENSE) + (size_t)p * NV;
  unsigned long long* d2o = (unsigned long long*)((char*)ws + OFF_D2O) + (size_t)p * RCAP;
  unsigned* rcnt = (unsigned*)((char*)ws + OFF_RCNT);
  float sgn = neg ? -1.f : 1.f;
  for (int i = tid; i < NV; i += 256) sm[i] = mono32(sgn * res[i]);
  __syncthreads();
  const int nd = neg ? 4 : 6;
  for (int v = tid; v < NV; v += 256) {
    int r = v / GN, c = v - r * GN;
    unsigned long long best = ((unsigned long long)sm[v] << 32) | (unsigned)~(unsigned)v;
    unsigned bi = (unsigned)v;
    bool cb[6] = { c < GN-1, c > 0, r < GN-1, r > 0,
                   (r < GN-1) && (c < GN-1), (r > 0) && (c > 0) };
    int  off[6] = { 1, -1, GN, -GN, GN+1, -(GN+1) };
    #pragma unroll
    for (int d = 0; d < 6; ++d) {
      if (d < nd && cb[d]) {
        unsigned y = (unsigned)(v + off[d]);
        unsigned long long o = ((unsigned long long)sm[y] << 32) | (unsigned)~y;
        if (o > best) { best = o; bi = y; }
      }
    }
    lab[v] = (unsigned short)bi;
  }
  __syncthreads();
  for (int v = tid; v < NV; v += 256) {
    unsigned r = lab[v];
    while (1) { unsigned n = lab[r]; if (n == r) break; r = n; }
    lab[v] = (unsigned short)r;
    glab[v] = (unsigned short)r;
  }
  __syncthreads();
  // dense rename of roots
  unsigned my = 0;
  for (int v = tid; v < NV; v += 256) if (lab[v] == (unsigned short)v) ++my;
  cnt[tid] = my;
  __syncthreads();
  for (int off = 1; off < 256; off <<= 1) {
    unsigned t = (tid >= off) ? cnt[tid - off] : 0u;
    __syncthreads();
    cnt[tid] += t;
    __syncthreads();
  }
  unsigned base = cnt[tid] - my;
  for (int v = tid; v < NV; v += 256) {
    if (lab[v] == (unsigned short)v) {
      if (base < RCAP) {
        dense[v] = (unsigned short)base;
        d2o[base] = ((unsigned long long)sm[v] << 32) | (unsigned)~(unsigned)v;
      }
      ++base;
    }
  }
  if (tid == 255) rcnt[p] = cnt[255];
}

// ---------------------------------------------------------------------------
// Kernel 3: boundary-edge hashing (dense pids, u32 events) + compaction
// ---------------------------------------------------------------------------
__global__ __launch_bounds__(256) void hash_k(float* ws) {
  __shared__ unsigned sm[NV];
  __shared__ unsigned hkey[HSZ];
  __shared__ unsigned hval[HSZ];
  __shared__ unsigned short lab[NV];
  __shared__ unsigned short dn[NV];
  __shared__ unsigned cnt[256];
  int p = blockIdx.x, samp = p >> 1, neg = p & 1, tid = threadIdx.x;
  const float* res = (const float*)((const char*)ws + OFF_RES) + samp * NV;
  const unsigned short* glab = (const unsigned short*)((const char*)ws + OFF_LAB) + (size_t)p * NV;
  const unsigned short* gdense = (const unsigned short*)((const char*)ws + OFF_DENSE) + (size_t)p * NV;
  unsigned long long* gedges = (unsigned long long*)((char*)ws + OFF_EDGES) + (size_t)p * HSZ;
  unsigned* ecnt = (unsigned*)((char*)ws + OFF_ECNT);
  float sgn = neg ? -1.f : 1.f;
  for (int i = tid; i < NV; i += 256) {
    sm[i] = mono32(sgn * res[i]); lab[i] = glab[i]; dn[i] = gdense[i];
  }
  for (int s = tid; s < HSZ; s += 256) { hkey[s] = EMPTYK; hval[s] = 0u; }
  __syncthreads();
  for (int v = tid; v < NV; v += 256) {
    int r = v / GN, c = v - r * GN;
    unsigned a = lab[v];
    unsigned sv = sm[v];
    bool vb[3] = { c < GN-1, r < GN-1, (!neg) && (r < GN-1) && (c < GN-1) };
    int  vo[3] = { 1, GN, GN+1 };
    #pragma unroll
    for (int d = 0; d < 3; ++d) {
      if (vb[d]) {
        unsigned w = (unsigned)(v + vo[d]);
        unsigned b = lab[w];
        if (a != b) {
          unsigned sw = sm[w];
          unsigned ev = (sv < sw) ? sv : sw;
          unsigned da = dn[a], db = dn[b];
          unsigned dlo = (da < db) ? da : db, dhi = (da < db) ? db : da;
          unsigned pid = (dlo << 16) | dhi;
          unsigned h = (pid * 2654435761u) >> 19;
          for (int pr2 = 0; pr2 < HSZ; ++pr2) {
            unsigned k = hkey[h];
            if (k == EMPTYK) {
              unsigned old = atomicCAS(&hkey[h], EMPTYK, pid);
              k = (old == EMPTYK) ? pid : old;
            }
            if (k == pid) { atomicMax(&hval[h], ev); break; }
            h = (h + 1) & HMASK;
          }
        }
      }
    }
  }
  __syncthreads();
  unsigned my = 0;
  for (int s = tid; s < HSZ; s += 256) if (hkey[s] != EMPTYK) ++my;
  cnt[tid] = my;
  __syncthreads();
  for (int off = 1; off < 256; off <<= 1) {
    unsigned t = (tid >= off) ? cnt[tid - off] : 0u;
    __syncthreads();
    cnt[tid] += t;
    __syncthreads();
  }
  unsigned base = cnt[tid] - my;
  for (int s = tid; s < HSZ; s += 256) {
    if (hkey[s] != EMPTYK) {
      gedges[base++] = ((unsigned long long)hval[s] << 32) | hkey[s];
    }
  }
  if (tid == 255) ecnt[p] = cnt[255];
}

// ---------------------------------------------------------------------------
// Kernel 4: histogram splitters (bin-aligned value-range buckets)
// ---------------------------------------------------------------------------
__global__ __launch_bounds__(256) void splitter_k(float* ws) {
  __shared__ unsigned hist[NBIN];
  __shared__ unsigned part[256];
  int p = blockIdx.x, tid = threadIdx.x;
  const unsigned long long* gedges = (const unsigned long long*)((const char*)ws + OFF_EDGES) + (size_t)p * HSZ;
  const unsigned* ecnt = (const unsigned*)((const char*)ws + OFF_ECNT);
  unsigned* Lrow = (unsigned*)((char*)ws + OFF_SPLIT) + p * KB;
  unsigned* lcnt = (unsigned*)((char*)ws + OFF_LCNT);
  unsigned E = ecnt[p]; if (E > HSZ) E = HSZ;
  for (int i = tid; i < NBIN; i += 256) hist[i] = 0u;
  __syncthreads();
  for (unsigned e = tid; e < E; e += 256) {
    unsigned bin = (unsigned)(gedges[e] >> 52);
    atomicAdd(&hist[bin], 1u);
  }
  __syncthreads();
  unsigned s = 0;
  #pragma unroll
  for (int i = 0; i < NBIN/256; ++i) s += hist[tid*(NBIN/256) + i];
  part[tid] = s;
  __syncthreads();
  for (int off = 1; off < 256; off <<= 1) {
    unsigned t = (tid + off < 256) ? part[tid + off] : 0u;
    __syncthreads();
    part[tid] += t;
    __syncthreads();
  }
  unsigned run = (tid == 255) ? 0u : part[tid + 1];
  for (int i = NBIN/256 - 1; i >= 0; --i) {
    int beta = tid*(NBIN/256) + i;
    run += hist[beta];
    hist[beta] = run;            // hist now = S(beta) = #edges with bin >= beta
  }
  __syncthreads();
  for (int m = 1; m < KB; ++m) {
    unsigned target = (unsigned)(((unsigned long long)m * E) / KB);
    #pragma unroll
    for (int i = 0; i < NBIN/256; ++i) {
      int beta = tid*(NBIN/256) + i;
      unsigned Sb = hist[beta];
      unsigned Sp = (beta == 0) ? 0xFFFFFFFFu : hist[beta - 1];
      if (Sb <= target && Sp > target) Lrow[m-1] = (unsigned)beta;
    }
    if (tid == 255 && hist[NBIN-1] > target) Lrow[m-1] = (unsigned)NBIN;
  }
  if (tid == 0) { Lrow[KB-1] = 0u; lcnt[p] = 0u; }
}

// ---------------------------------------------------------------------------
// Kernel 5: bucketed elder-rule Kruskal. One block per (problem, bucket).
//  prefix = order-free edge SET (bin >= Lhi) -> parallel min-hook CC + peaks
//  own edges (Llo <= bin < Lhi) sorted locally, then serial Kruskal.
// ---------------------------------------------------------------------------
__global__ __launch_bounds__(256) void kruskal_bucket_k(float* ws) {
  __shared__ unsigned pre[HSZ];                 // 32KB prefix pids
  __shared__ unsigned long long my[MYCAP + 1];  // 32KB own edges
  __shared__ unsigned par[RCAP];                // 24KB
  __shared__ unsigned long long peak[RCAP];     // 48KB
  __shared__ unsigned mycnt, precnt;
  __shared__ int flag;
  int p = blockIdx.x / KB, bk = blockIdx.x % KB, tid = threadIdx.x;
  const unsigned long long* gedges = (const unsigned long long*)((const char*)ws + OFF_EDGES) + (size_t)p * HSZ;
  const unsigned long long* d2o = (const unsigned long long*)((const char*)ws + OFF_D2O) + (size_t)p * RCAP;
  const unsigned* ecnt = (const unsigned*)((const char*)ws + OFF_ECNT);
  const unsigned* rcnt = (const unsigned*)((const char*)ws + OFF_RCNT);
  const unsigned* Lrow = (const unsigned*)((const char*)ws + OFF_SPLIT) + p * KB;
  unsigned* lcnt = (unsigned*)((char*)ws + OFF_LCNT);
  float* glist = (float*)((char*)ws + OFF_LIST) + (size_t)p * LISTCAP;
  unsigned E = ecnt[p]; if (E > HSZ) E = HSZ;
  unsigned R = rcnt[p]; if (R > RCAP) R = RCAP;
  unsigned Llo = Lrow[bk];
  unsigned Lhi = (bk == 0) ? (unsigned)NBIN : Lrow[bk - 1];
  if (tid == 0) { mycnt = 0; precnt = 0; }
  for (unsigned d = tid; d < R; d += 256) { par[d] = d; peak[d] = d2o[d]; }
  __syncthreads();
  // classify edges
  for (unsigned e = tid; e < E; e += 256) {
    unsigned long long it = gedges[e];
    unsigned bin = (unsigned)(it >> 52);
    if (bin >= Lhi) {
      unsigned k = atomicAdd(&precnt, 1u);
      pre[k] = (unsigned)it;
    } else if (bin >= Llo) {
      unsigned k = atomicAdd(&mycnt, 1u);
      if (k < MYCAP) my[k] = it;
    }
  }
  __syncthreads();
  unsigned mc = mycnt; if (mc > MYCAP) mc = MYCAP;
  unsigned pc = precnt;
  int S2 = 2; while (S2 < (int)mc) S2 <<= 1;
  for (unsigned i = mc + tid; i <= MYCAP; i += 256) my[i] = 0ull;  // pad + sentinel
  __syncthreads();
  // local bitonic sort (desc) of own edges
  for (int k = 2; k <= S2; k <<= 1) {
    for (int j = k >> 1; j > 0; j >>= 1) {
      for (int i = tid; i < S2; i += 256) {
        int l = i ^ j;
        if (l > i) {
          unsigned long long a = my[i], b = my[l];
          bool up = ((i & k) == 0);
          if (up ? (a < b) : (a > b)) { my[i] = b; my[l] = a; }
        }
      }
      __syncthreads();
    }
  }
  // parallel CC over prefix set
  while (1) {
    if (tid == 0) flag = 0;
    __syncthreads();
    for (unsigned e = tid; e < pc; e += 256) {
      unsigned pid = pre[e];
      unsigned a = pid >> 16, b = pid & 0xffffu;
      unsigned ra = a; while (par[ra] != ra) ra = par[ra];
      unsigned rb = b; while (par[rb] != rb) rb = par[rb];
      if (ra != rb) {
        unsigned mn = (ra < rb) ? ra : rb, mx = (ra < rb) ? rb : ra;
        atomicMin(&par[mx], mn);
        flag = 1;
      }
    }
    __syncthreads();
    if (!flag) break;
    for (unsigned d = tid; d < R; d += 256) {
      unsigned r = d; while (par[r] != r) r = par[r];
      par[d] = r;
    }
    __syncthreads();
  }
  // component peak ords
  for (unsigned d = tid; d < R; d += 256) {
    unsigned r = par[d];
    if (r != d) atomicMax(&peak[r], peak[d]);
  }
  __syncthreads();
  // serial Kruskal over own sorted edges
  if (tid != 0) return;
  unsigned long long it = my[0];
  for (unsigned e = 0; e < mc; ++e) {
    unsigned long long nx = my[e + 1];
    unsigned ev = (unsigned)(it >> 32);
    unsigned pid = (unsigned)it;
    unsigned ca = pid >> 16, cb = pid & 0xffffu;
    while (1) {
      unsigned pa = par[ca], pb = par[cb];
      bool da = (pa == ca), db = (pb == cb);
      if (da && db) break;
      unsigned ga = par[pa], gb = par[pb];
      if (!da) { par[ca] = ga; ca = ga; }
      if (!db) { par[cb] = gb; cb = gb; }
    }
    if (ca != cb) {
      unsigned long long pa = peak[ca], pb = peak[cb];
      unsigned win = (pa >= pb) ? ca : cb;
      unsigned los = (pa >= pb) ? cb : ca;
      unsigned long long lord = (pa >= pb) ? pb : pa;
      float bar = unmono((unsigned)(lord >> 32)) - unmono(ev);
      unsigned idx = atomicAdd(&lcnt[p], 1u);
      if (idx < LISTCAP) glist[idx] = bar;
      par[los] = win;
    }
    it = nx;
  }
}

// ---------------------------------------------------------------------------
// Kernel 6: per-problem top-20 over compact bar list -> partial[p]
// ---------------------------------------------------------------------------
__global__ __launch_bounds__(256) void topk_k(float* ws) {
  __shared__ float sl[LISTCAP];
  __shared__ float rv[256];
  __shared__ int   ri[256];
  int p = blockIdx.x, tid = threadIdx.x;
  const float* glist = (const float*)((const char*)ws + OFF_LIST) + (size_t)p * LISTCAP;
  const unsigned* lcnt = (const unsigned*)((const char*)ws + OFF_LCNT);
  float* part = (float*)((char*)ws + OFF_PART);
  unsigned cnt = lcnt[p]; if (cnt > LISTCAP) cnt = LISTCAP;
  for (int i = tid; i < LISTCAP; i += 256) sl[i] = (i < (int)cnt) ? glist[i] : 0.f;
  __syncthreads();
  float acc = 0.f;
  for (int k = 0; k < K_TOP; ++k) {
    float mv = -1.f; int mi = LISTCAP;
    for (int i = tid; i < LISTCAP; i += 256) {
      float v = sl[i];
      if (v > mv) { mv = v; mi = i; }
    }
    rv[tid] = mv; ri[tid] = mi;
    __syncthreads();
    for (int s = 128; s > 0; s >>= 1) {
      if (tid < s) {
        if (rv[tid+s] > rv[tid] || (rv[tid+s] == rv[tid] && ri[tid+s] < ri[tid])) {
          rv[tid] = rv[tid+s]; ri[tid] = ri[tid+s];
        }
      }
      __syncthreads();
    }
    if (tid == 0) {
      float best = rv[0] > 0.f ? rv[0] : 0.f;   // pad with zeros like reference
      float sgnk = (k < 5) ? -1.f : 1.f;
      acc += sgnk * best * best;
      if (ri[0] < LISTCAP) sl[ri[0]] = -2.f;
    }
    __syncthreads();
  }
  if (tid == 0) part[p] = acc;
}

// ---------------------------------------------------------------------------
// Kernel 7: deterministic final reduction (mean over batch)
// ---------------------------------------------------------------------------
__global__ void final_k(float* ws, float* out) {
  if (threadIdx.x == 0 && blockIdx.x == 0) {
    const float* part = (const float*)((const char*)ws + OFF_PART);
    float s = 0.f;
    for (int i = 0; i < NPROB; ++i) s += part[i];
    out[0] = s / (float)NB;
  }
}

extern "C" void kernel_launch(void* const* d_in, const int* in_sizes, int n_in,
                              void* d_out, int out_size, void* d_ws, size_t ws_size,
                              hipStream_t stream) {
  const float* in = (const float*)d_in[0];
  float* ws = (float*)d_ws;
  float* out = (float*)d_out;
  hipLaunchKernelGGL(resize_k, dim3((NB * NV + 255) / 256), dim3(256), 0, stream, in, ws);
  hipLaunchKernelGGL(label_rename_k, dim3(NPROB), dim3(256), 0, stream, ws);
  hipLaunchKernelGGL(hash_k, dim3(NPROB), dim3(256), 0, stream, ws);
  hipLaunchKernelGGL(splitter_k, dim3(NPROB), dim3(256), 0, stream, ws);
  hipLaunchKernelGGL(kruskal_bucket_k, dim3(NPROB * KB), dim3(256), 0, stream, ws);
  hipLaunchKernelGGL(topk_k, dim3(NPROB), dim3(256), 0, stream, ws);
  hipLaunchKernelGGL(final_k, dim3(1), dim3(64), 0, stream, ws, out);
}